// Round 3
// baseline (207.140 us; speedup 1.0000x reference)
//
#include <hip/hip_runtime.h>
#include <math.h>

#define EPSF 1e-5f

typedef __attribute__((ext_vector_type(8))) __bf16 bf16x8;
typedef __attribute__((ext_vector_type(4))) float f32x4;

__device__ __forceinline__ unsigned short f2bf(float f) {
  unsigned int u = __float_as_uint(f);
  u += 0x7FFFu + ((u >> 16) & 1u);
  return (unsigned short)(u >> 16);
}

__device__ __forceinline__ void async_load16(const void* g, void* l) {
  __builtin_amdgcn_global_load_lds(
      (const __attribute__((address_space(1))) void*)g,
      (__attribute__((address_space(3))) void*)l, 16, 0, 0);
}

// ---- fused dual transpose fp32->bf16, vectorized: dst[c][r] = bf16(src[r][c])
// blocks [0,1024): W1 1024x4096 ; [1024,2048): W2 4096x1024. 64x64 tiles.
__global__ __launch_bounds__(256) void k_transpose2(
    const float* __restrict__ W1, unsigned short* __restrict__ W1t,
    const float* __restrict__ W2, unsigned short* __restrict__ W2t) {
  __shared__ float tile[64][65];
  const float* src; unsigned short* dst; int R, C, r0, c0;
  int bid = blockIdx.x;
  if (bid < 1024) { src = W1; dst = W1t; R = 1024; C = 4096;
                    c0 = (bid & 63) * 64; r0 = (bid >> 6) * 64; }
  else { bid -= 1024; src = W2; dst = W2t; R = 4096; C = 1024;
         c0 = (bid & 15) * 64; r0 = (bid >> 4) * 64; }
  int tid = threadIdx.x;
  #pragma unroll
  for (int q = 0; q < 4; ++q) {
    int lin = q * 256 + tid;
    int r = lin >> 4, cq = lin & 15;
    float4 v = *(const float4*)(src + (size_t)(r0 + r) * C + c0 + cq * 4);
    tile[r][cq * 4 + 0] = v.x; tile[r][cq * 4 + 1] = v.y;
    tile[r][cq * 4 + 2] = v.z; tile[r][cq * 4 + 3] = v.w;
  }
  __syncthreads();
  #pragma unroll
  for (int q = 0; q < 4; ++q) {
    int lin = q * 256 + tid;
    int c = lin >> 4, rq = lin & 15;
    ushort4 o;
    o.x = f2bf(tile[rq * 4 + 0][c]);
    o.y = f2bf(tile[rq * 4 + 1][c]);
    o.z = f2bf(tile[rq * 4 + 2][c]);
    o.w = f2bf(tile[rq * 4 + 3][c]);
    *(ushort4*)(dst + (size_t)(c0 + c) * R + r0 + rq * 4) = o;
  }
}

// ---- LN over 1024 elems per (b,s) + dt head -> xn (fp32), log_a ----
__global__ __launch_bounds__(256) void k_ln_dt(
    const float* __restrict__ x, const float* __restrict__ g, const float* __restrict__ bta,
    const float* __restrict__ w_dt, const float* __restrict__ b_dt,
    const float* __restrict__ log_A,
    float* __restrict__ xn, float* __restrict__ log_a) {
  int bs = blockIdx.x;
  int t = threadIdx.x;
  float4 v = ((const float4*)(x + (size_t)bs * 1024))[t];
  float s = v.x + v.y + v.z + v.w;
  float ss = v.x * v.x + v.y * v.y + v.z * v.z + v.w * v.w;
  #pragma unroll
  for (int o = 1; o < 64; o <<= 1) { s += __shfl_xor(s, o); ss += __shfl_xor(ss, o); }
  __shared__ float red[8];
  int w = t >> 6;
  if ((t & 63) == 0) { red[w] = s; red[4 + w] = ss; }
  __syncthreads();
  float S = red[0] + red[1] + red[2] + red[3];
  float SS = red[4] + red[5] + red[6] + red[7];
  float m = S * (1.0f / 1024.0f);
  float var = SS * (1.0f / 1024.0f) - m * m;
  float inv = rsqrtf(var + EPSF);
  float4 gv = ((const float4*)g)[t];
  float4 bv = ((const float4*)bta)[t];
  float4 o;
  o.x = (v.x - m) * inv * gv.x + bv.x;
  o.y = (v.y - m) * inv * gv.y + bv.y;
  o.z = (v.z - m) * inv * gv.z + bv.z;
  o.w = (v.w - m) * inv * gv.w + bv.w;
  ((float4*)(xn + (size_t)bs * 1024))[t] = o;
  float4 wv = ((const float4*)w_dt)[t & 7];
  float part = o.x * wv.x + o.y * wv.y + o.z * wv.z + o.w * wv.w;
  part += __shfl_xor(part, 1);
  part += __shfl_xor(part, 2);
  part += __shfl_xor(part, 4);
  if ((t & 7) == 0) {
    int r = t >> 3;
    float z = part + b_dt[0];
    float sp = (z > 20.0f) ? z : log1pf(expf(z));
    log_a[(size_t)bs * 32 + r] = sp * (-expf(log_A[r]));
  }
}

// ---- chunked scan, float4 over c. grid (b,r,ch)=512; 256 thr = 32 sub x 8 cg
// sub chain = 4 timesteps. PASS0: chunk (E,P). PASS1: full scan + residual.
template <int PASS>
__global__ __launch_bounds__(256) void k_scan_pass(
    const float* __restrict__ xn, const float* __restrict__ x,
    const float* __restrict__ loga, float4* __restrict__ E, float* __restrict__ P,
    float* __restrict__ ssm) {
  int bx = blockIdx.x;
  int b = bx >> 8, r = (bx >> 3) & 31, ch = bx & 7;
  int tid = threadIdx.x, cg = tid & 7, sub = tid >> 3;
  __shared__ float dec[128];
  __shared__ float4 sE[32][8];
  __shared__ float sP[32];
  if (tid < 128)
    dec[tid] = expf(loga[(size_t)(b * 1024 + ch * 128 + tid) * 32 + r]);
  __syncthreads();
  int t0 = ch * 128 + sub * 4;
  size_t base = ((size_t)(b * 1024 + t0) * 1024 + r * 32 + cg * 4) >> 2;  // float4 idx
  const float4* xn4 = (const float4*)xn;
  float4 xv[4];
  #pragma unroll
  for (int i = 0; i < 4; ++i) xv[i] = xn4[base + (size_t)i * 256];
  float4 S = {0.f, 0.f, 0.f, 0.f};
  float Pl = 1.0f;
  #pragma unroll
  for (int i = 0; i < 4; ++i) {
    float d = dec[sub * 4 + i];
    S.x = d * S.x + xv[i].x; S.y = d * S.y + xv[i].y;
    S.z = d * S.z + xv[i].z; S.w = d * S.w + xv[i].w;
    Pl *= d;
  }
  sE[sub][cg] = S;
  if (cg == 0) sP[sub] = Pl;
  __syncthreads();
  if (PASS == 0) {
    if (tid < 8) {
      float4 Et = {0.f, 0.f, 0.f, 0.f};
      float PP = 1.0f;
      #pragma unroll
      for (int h = 0; h < 32; ++h) {
        float p = sP[h]; float4 e = sE[h][tid];
        Et.x = p * Et.x + e.x; Et.y = p * Et.y + e.y;
        Et.z = p * Et.z + e.z; Et.w = p * Et.w + e.w;
        PP *= p;
      }
      E[((size_t)(b * 32 + r) * 8 + ch) * 8 + tid] = Et;
      if (tid == 0) P[(b * 32 + r) * 8 + ch] = PP;
    }
  } else {
    float4 Sin = {0.f, 0.f, 0.f, 0.f};
    const float4* Eb = E + (size_t)(b * 32 + r) * 64 + cg;
    const float* Pb = P + (size_t)(b * 32 + r) * 8;
    for (int h = 0; h < ch; ++h) {
      float p = Pb[h]; float4 e = Eb[h * 8];
      Sin.x = p * Sin.x + e.x; Sin.y = p * Sin.y + e.y;
      Sin.z = p * Sin.z + e.z; Sin.w = p * Sin.w + e.w;
    }
    for (int h = 0; h < sub; ++h) {
      float p = sP[h]; float4 e = sE[h][cg];
      Sin.x = p * Sin.x + e.x; Sin.y = p * Sin.y + e.y;
      Sin.z = p * Sin.z + e.z; Sin.w = p * Sin.w + e.w;
    }
    const float4* x4 = (const float4*)x;
    float4* ssm4 = (float4*)ssm;
    #pragma unroll
    for (int i = 0; i < 4; ++i) {
      float d = dec[sub * 4 + i];
      Sin.x = d * Sin.x + xv[i].x; Sin.y = d * Sin.y + xv[i].y;
      Sin.z = d * Sin.z + xv[i].z; Sin.w = d * Sin.w + xv[i].w;
      float4 rx = x4[base + (size_t)i * 256];
      float4 o;
      o.x = Sin.x + rx.x; o.y = Sin.y + rx.y;
      o.z = Sin.z + rx.z; o.w = Sin.w + rx.w;
      ssm4[base + (size_t)i * 256] = o;
    }
  }
}

// ---- LN2 -> fn bf16 ----
__global__ __launch_bounds__(256) void k_ln2(
    const float* __restrict__ ssm, const float* __restrict__ g, const float* __restrict__ bta,
    unsigned short* __restrict__ fn) {
  int bs = blockIdx.x;
  int t = threadIdx.x;
  float4 v = ((const float4*)(ssm + (size_t)bs * 1024))[t];
  float s = v.x + v.y + v.z + v.w;
  float ss = v.x * v.x + v.y * v.y + v.z * v.z + v.w * v.w;
  #pragma unroll
  for (int o = 1; o < 64; o <<= 1) { s += __shfl_xor(s, o); ss += __shfl_xor(ss, o); }
  __shared__ float red[8];
  int w = t >> 6;
  if ((t & 63) == 0) { red[w] = s; red[4 + w] = ss; }
  __syncthreads();
  float S = red[0] + red[1] + red[2] + red[3];
  float SS = red[4] + red[5] + red[6] + red[7];
  float m = S * (1.0f / 1024.0f);
  float var = SS * (1.0f / 1024.0f) - m * m;
  float inv = rsqrtf(var + EPSF);
  float4 gv = ((const float4*)g)[t];
  float4 bv = ((const float4*)bta)[t];
  ushort4 o;
  o.x = f2bf((v.x - m) * inv * gv.x + bv.x);
  o.y = f2bf((v.y - m) * inv * gv.y + bv.y);
  o.z = f2bf((v.z - m) * inv * gv.z + bv.z);
  o.w = f2bf((v.w - m) * inv * gv.w + bv.w);
  ((ushort4*)(fn + (size_t)bs * 1024))[t] = o;
}

// ---- m97-style bf16 MFMA GEMM, XCD-partitioned 1D grid (512 blocks).
// BM=128. EPI 0 (BN=128): gelu->bf16; XCD by n-panel (B L2-resident).
// EPI 1 (BN=64): fp32 split-K=2 partials; XCD by m-pair (A L2-resident).
template <int BN, int EPI>
__global__ __launch_bounds__(256) void k_gemm(
    const unsigned short* __restrict__ A, const unsigned short* __restrict__ Bt,
    const float* __restrict__ bias, void* __restrict__ C,
    int M, int N, int K) {
  constexpr int WN = BN / 2;        // wave n-extent
  constexpr int NJ = BN / 32;       // 16-wide n-frags per wave
  __shared__ __align__(16) unsigned short sA[128 * 32];
  __shared__ __align__(16) unsigned short sB[BN * 32];
  int L = blockIdx.x;
  int m0, n0, kOff, kLen, ks = 0;
  if (EPI == 0) {                    // 32 n-tiles x 16 m-tiles
    n0 = ((L & 7) * 4 + ((L >> 3) & 3)) * 128;
    m0 = (L >> 5) * 128;
    kOff = 0; kLen = K;
  } else {                           // 16 m-tiles x 16 n-tiles x 2 ks
    m0 = ((L & 7) * 2 + ((L >> 3) & 1)) * 128;
    int rest = L >> 4;
    n0 = (rest & 15) * BN;
    ks = rest >> 4;
    kLen = K >> 1; kOff = ks * kLen;
  }
  int tid = threadIdx.x;
  int wave = tid >> 6, lane = tid & 63;
  int wr = wave >> 1, wc = wave & 1;
  int l15 = lane & 15, quad = lane >> 4;

  const unsigned short* gA0 = A + (size_t)(m0 + (tid >> 2)) * K + kOff + (tid & 3) * 8;
  const unsigned short* gA1 = gA0 + (size_t)64 * K;
  const unsigned short* gB0 = Bt + (size_t)(n0 + (tid >> 2)) * K + kOff + (tid & 3) * 8;
  const unsigned short* gB1 = gB0 + (size_t)64 * K;   // only used when BN==128
  unsigned short* lA0 = sA + (size_t)(tid & ~63) * 8;
  unsigned short* lA1 = lA0 + 256 * 8;
  unsigned short* lB0 = sB + (size_t)(tid & ~63) * 8;
  unsigned short* lB1 = lB0 + 256 * 8;

  f32x4 zero = {0.0f, 0.0f, 0.0f, 0.0f};
  f32x4 acc[4][NJ];
  #pragma unroll
  for (int i = 0; i < 4; ++i)
    #pragma unroll
    for (int j = 0; j < NJ; ++j) acc[i][j] = zero;

  const unsigned short* pa = sA + (wr * 64 + l15) * 32 + quad * 8;
  const unsigned short* pb = sB + (wc * WN + l15) * 32 + quad * 8;

  for (int k0 = 0; k0 < kLen; k0 += 32) {
    async_load16(gA0, lA0);
    async_load16(gA1, lA1);
    async_load16(gB0, lB0);
    if (BN == 128) async_load16(gB1, lB1);
    gA0 += 32; gA1 += 32; gB0 += 32; gB1 += 32;
    __syncthreads();
    bf16x8 af[4], bfr[NJ];
    #pragma unroll
    for (int i = 0; i < 4; ++i) af[i] = *(const bf16x8*)(pa + i * 512);
    #pragma unroll
    for (int j = 0; j < NJ; ++j) bfr[j] = *(const bf16x8*)(pb + j * 512);
    #pragma unroll
    for (int i = 0; i < 4; ++i)
      #pragma unroll
      for (int j = 0; j < NJ; ++j)
        acc[i][j] = __builtin_amdgcn_mfma_f32_16x16x32_bf16(af[i], bfr[j], acc[i][j], 0, 0, 0);
    __syncthreads();
  }

  if (EPI == 0) {
    unsigned short* Cb = (unsigned short*)C;
    #pragma unroll
    for (int i = 0; i < 4; ++i)
      #pragma unroll
      for (int j = 0; j < NJ; ++j) {
        int col = n0 + wc * WN + j * 16 + l15;
        float bval = bias[col];
        #pragma unroll
        for (int v = 0; v < 4; ++v) {
          int row = m0 + wr * 64 + i * 16 + quad * 4 + v;
          float val = acc[i][j][v] + bval;
          val = 0.5f * val * (1.0f + erff(val * 0.70710678118654752f));
          Cb[(size_t)row * N + col] = f2bf(val);
        }
      }
  } else {
    float* dst = (float*)C + (size_t)ks * M * N;
    #pragma unroll
    for (int i = 0; i < 4; ++i)
      #pragma unroll
      for (int j = 0; j < NJ; ++j) {
        int col = n0 + wc * WN + j * 16 + l15;
        #pragma unroll
        for (int v = 0; v < 4; ++v) {
          int row = m0 + wr * 64 + i * 16 + quad * 4 + v;
          dst[(size_t)row * N + col] = acc[i][j][v];
        }
      }
  }
}

// ---- split-K=2 reduce + bias + residual ----
__global__ __launch_bounds__(256) void k_reduce(
    const float* __restrict__ pA, const float* __restrict__ bias,
    const float* __restrict__ res, float* __restrict__ out) {
  int i = blockIdx.x * 256 + threadIdx.x;  // float4 index; MN/4 = 524288
  const int MN4 = 524288;
  float4 v = ((const float4*)pA)[i];
  float4 w = ((const float4*)pA)[i + MN4];
  float4 bb = ((const float4*)bias)[i & 255];
  float4 rr = ((const float4*)res)[i];
  float4 o;
  o.x = v.x + w.x + bb.x + rr.x; o.y = v.y + w.y + bb.y + rr.y;
  o.z = v.z + w.z + bb.z + rr.z; o.w = v.w + w.w + bb.w + rr.w;
  ((float4*)out)[i] = o;
}

extern "C" void kernel_launch(void* const* d_in, const int* in_sizes, int n_in,
                              void* d_out, int out_size, void* d_ws, size_t ws_size,
                              hipStream_t stream) {
  const float* x     = (const float*)d_in[0];
  const float* log_A = (const float*)d_in[1];
  const float* w_dt  = (const float*)d_in[2];
  const float* b_dt  = (const float*)d_in[3];
  const float* g_ssm = (const float*)d_in[4];
  const float* b_ssm = (const float*)d_in[5];
  const float* g_ffn = (const float*)d_in[6];
  const float* b_ffn = (const float*)d_in[7];
  const float* W1    = (const float*)d_in[8];
  const float* bb1   = (const float*)d_in[9];
  const float* W2    = (const float*)d_in[10];
  const float* bb2   = (const float*)d_in[11];
  float* out = (float*)d_out;

  const size_t MB = 1u << 20;
  char* ws = (char*)d_ws;
  float* xn            = (float*)(ws);                     // 8 MB (dies after scan p1)
  unsigned short* W1t  = (unsigned short*)(ws + 8 * MB);   // 8 MB (dies after gemm1)
  float* loga          = (float*)(ws + 16 * MB);           // 256 KB
  float4* Ebuf         = (float4*)(ws + 17 * MB);          // 64 KB
  float* Pbuf          = (float*)(ws + 17 * MB + 131072);  // 2 KB
  unsigned short* fn   = (unsigned short*)(ws + 18 * MB);  // 4 MB
  float* ssm           = (float*)(ws + 22 * MB);           // 8 MB (live to end)
  unsigned short* W2t  = (unsigned short*)(ws + 30 * MB);  // 8 MB
  unsigned short* hbf  = (unsigned short*)(ws + 38 * MB);  // 16 MB -> 54 MB total
  float* pA = (float*)(ws);                                // 16 MB over xn+W1t

  k_transpose2<<<2048, 256, 0, stream>>>(W1, W1t, W2, W2t);
  k_ln_dt<<<2048, 256, 0, stream>>>(x, g_ssm, b_ssm, w_dt, b_dt, log_A, xn, loga);
  k_scan_pass<0><<<512, 256, 0, stream>>>(xn, x, loga, Ebuf, Pbuf, ssm);
  k_scan_pass<1><<<512, 256, 0, stream>>>(xn, x, loga, Ebuf, Pbuf, ssm);
  k_ln2<<<2048, 256, 0, stream>>>(ssm, g_ffn, b_ffn, fn);
  k_gemm<128, 0><<<512, 256, 0, stream>>>(fn, W1t, bb1, (void*)hbf, 2048, 4096, 1024);
  k_gemm<64, 1><<<512, 256, 0, stream>>>(hbf, W2t, nullptr, (void*)pA, 2048, 1024, 4096);
  k_reduce<<<2048, 256, 0, stream>>>(pA, bb2, ssm, out);
}

// Round 4
// 204.566 us; speedup vs baseline: 1.0126x; 1.0126x over previous
//
#include <hip/hip_runtime.h>
#include <math.h>

#define EPSF 1e-5f

typedef __attribute__((ext_vector_type(8))) __bf16 bf16x8;
typedef __attribute__((ext_vector_type(4))) float f32x4;

__device__ __forceinline__ unsigned short f2bf(float f) {
  unsigned int u = __float_as_uint(f);
  u += 0x7FFFu + ((u >> 16) & 1u);
  return (unsigned short)(u >> 16);
}

__device__ __forceinline__ void async_load16(const void* g, void* l) {
  __builtin_amdgcn_global_load_lds(
      (const __attribute__((address_space(1))) void*)g,
      (__attribute__((address_space(3))) void*)l, 16, 0, 0);
}

// ---- fused: LN1+dt (blocks 0..2047) | weight transpose fp32->bf16 (2048..4095)
__global__ __launch_bounds__(256) void k_pre(
    const float* __restrict__ x, const float* __restrict__ g, const float* __restrict__ bta,
    const float* __restrict__ w_dt, const float* __restrict__ b_dt,
    const float* __restrict__ log_A, float* __restrict__ xn, float* __restrict__ log_a,
    const float* __restrict__ W1, unsigned short* __restrict__ W1t,
    const float* __restrict__ W2, unsigned short* __restrict__ W2t) {
  __shared__ float smem[64 * 65];
  int tid = threadIdx.x;
  if (blockIdx.x < 2048) {
    int bs = blockIdx.x;
    int t = tid;
    float4 v = ((const float4*)(x + (size_t)bs * 1024))[t];
    float s = v.x + v.y + v.z + v.w;
    float ss = v.x * v.x + v.y * v.y + v.z * v.z + v.w * v.w;
    #pragma unroll
    for (int o = 1; o < 64; o <<= 1) { s += __shfl_xor(s, o); ss += __shfl_xor(ss, o); }
    float* red = smem;
    int w = t >> 6;
    if ((t & 63) == 0) { red[w] = s; red[4 + w] = ss; }
    __syncthreads();
    float S = red[0] + red[1] + red[2] + red[3];
    float SS = red[4] + red[5] + red[6] + red[7];
    float m = S * (1.0f / 1024.0f);
    float var = SS * (1.0f / 1024.0f) - m * m;
    float inv = rsqrtf(var + EPSF);
    float4 gv = ((const float4*)g)[t];
    float4 bv = ((const float4*)bta)[t];
    float4 o;
    o.x = (v.x - m) * inv * gv.x + bv.x;
    o.y = (v.y - m) * inv * gv.y + bv.y;
    o.z = (v.z - m) * inv * gv.z + bv.z;
    o.w = (v.w - m) * inv * gv.w + bv.w;
    ((float4*)(xn + (size_t)bs * 1024))[t] = o;
    float4 wv = ((const float4*)w_dt)[t & 7];
    float part = o.x * wv.x + o.y * wv.y + o.z * wv.z + o.w * wv.w;
    part += __shfl_xor(part, 1);
    part += __shfl_xor(part, 2);
    part += __shfl_xor(part, 4);
    if ((t & 7) == 0) {
      int r = t >> 3;
      float z = part + b_dt[0];
      float sp = (z > 20.0f) ? z : log1pf(expf(z));
      log_a[(size_t)bs * 32 + r] = sp * (-expf(log_A[r]));
    }
  } else {
    int bid = blockIdx.x - 2048;
    const float* src; unsigned short* dst; int R, C, r0, c0;
    if (bid < 1024) { src = W1; dst = W1t; R = 1024; C = 4096;
                      c0 = (bid & 63) * 64; r0 = (bid >> 6) * 64; }
    else { bid -= 1024; src = W2; dst = W2t; R = 4096; C = 1024;
           c0 = (bid & 15) * 64; r0 = (bid >> 4) * 64; }
    #pragma unroll
    for (int q = 0; q < 4; ++q) {
      int lin = q * 256 + tid;
      int r = lin >> 4, cq = lin & 15;
      float4 v = *(const float4*)(src + (size_t)(r0 + r) * C + c0 + cq * 4);
      smem[r * 65 + cq * 4 + 0] = v.x; smem[r * 65 + cq * 4 + 1] = v.y;
      smem[r * 65 + cq * 4 + 2] = v.z; smem[r * 65 + cq * 4 + 3] = v.w;
    }
    __syncthreads();
    #pragma unroll
    for (int q = 0; q < 4; ++q) {
      int lin = q * 256 + tid;
      int c = lin >> 4, rq = lin & 15;
      ushort4 o;
      o.x = f2bf(smem[(rq * 4 + 0) * 65 + c]);
      o.y = f2bf(smem[(rq * 4 + 1) * 65 + c]);
      o.z = f2bf(smem[(rq * 4 + 2) * 65 + c]);
      o.w = f2bf(smem[(rq * 4 + 3) * 65 + c]);
      *(ushort4*)(dst + (size_t)(c0 + c) * R + r0 + rq * 4) = o;
    }
  }
}

// ---- chunked scan, float4 over c. grid (b,r,ch)=512; 256 thr = 32 sub x 8 cg
template <int PASS>
__global__ __launch_bounds__(256) void k_scan_pass(
    const float* __restrict__ xn, const float* __restrict__ x,
    const float* __restrict__ loga, float4* __restrict__ E, float* __restrict__ P,
    float* __restrict__ ssm) {
  int bx = blockIdx.x;
  int b = bx >> 8, r = (bx >> 3) & 31, ch = bx & 7;
  int tid = threadIdx.x, cg = tid & 7, sub = tid >> 3;
  __shared__ float dec[128];
  __shared__ float4 sE[32][8];
  __shared__ float sP[32];
  if (tid < 128)
    dec[tid] = expf(loga[(size_t)(b * 1024 + ch * 128 + tid) * 32 + r]);
  __syncthreads();
  int t0 = ch * 128 + sub * 4;
  size_t base = ((size_t)(b * 1024 + t0) * 1024 + r * 32 + cg * 4) >> 2;
  const float4* xn4 = (const float4*)xn;
  float4 xv[4];
  #pragma unroll
  for (int i = 0; i < 4; ++i) xv[i] = xn4[base + (size_t)i * 256];
  float4 S = {0.f, 0.f, 0.f, 0.f};
  float Pl = 1.0f;
  #pragma unroll
  for (int i = 0; i < 4; ++i) {
    float d = dec[sub * 4 + i];
    S.x = d * S.x + xv[i].x; S.y = d * S.y + xv[i].y;
    S.z = d * S.z + xv[i].z; S.w = d * S.w + xv[i].w;
    Pl *= d;
  }
  sE[sub][cg] = S;
  if (cg == 0) sP[sub] = Pl;
  __syncthreads();
  if (PASS == 0) {
    if (tid < 8) {
      float4 Et = {0.f, 0.f, 0.f, 0.f};
      float PP = 1.0f;
      #pragma unroll
      for (int h = 0; h < 32; ++h) {
        float p = sP[h]; float4 e = sE[h][tid];
        Et.x = p * Et.x + e.x; Et.y = p * Et.y + e.y;
        Et.z = p * Et.z + e.z; Et.w = p * Et.w + e.w;
        PP *= p;
      }
      E[((size_t)(b * 32 + r) * 8 + ch) * 8 + tid] = Et;
      if (tid == 0) P[(b * 32 + r) * 8 + ch] = PP;
    }
  } else {
    float4 Sin = {0.f, 0.f, 0.f, 0.f};
    const float4* Eb = E + (size_t)(b * 32 + r) * 64 + cg;
    const float* Pb = P + (size_t)(b * 32 + r) * 8;
    for (int h = 0; h < ch; ++h) {
      float p = Pb[h]; float4 e = Eb[h * 8];
      Sin.x = p * Sin.x + e.x; Sin.y = p * Sin.y + e.y;
      Sin.z = p * Sin.z + e.z; Sin.w = p * Sin.w + e.w;
    }
    for (int h = 0; h < sub; ++h) {
      float p = sP[h]; float4 e = sE[h][cg];
      Sin.x = p * Sin.x + e.x; Sin.y = p * Sin.y + e.y;
      Sin.z = p * Sin.z + e.z; Sin.w = p * Sin.w + e.w;
    }
    const float4* x4 = (const float4*)x;
    float4* ssm4 = (float4*)ssm;
    #pragma unroll
    for (int i = 0; i < 4; ++i) {
      float d = dec[sub * 4 + i];
      Sin.x = d * Sin.x + xv[i].x; Sin.y = d * Sin.y + xv[i].y;
      Sin.z = d * Sin.z + xv[i].z; Sin.w = d * Sin.w + xv[i].w;
      float4 rx = x4[base + (size_t)i * 256];
      float4 o;
      o.x = Sin.x + rx.x; o.y = Sin.y + rx.y;
      o.z = Sin.z + rx.z; o.w = Sin.w + rx.w;
      ssm4[base + (size_t)i * 256] = o;
    }
  }
}

// ---- LN2 -> fn bf16 ----
__global__ __launch_bounds__(256) void k_ln2(
    const float* __restrict__ ssm, const float* __restrict__ g, const float* __restrict__ bta,
    unsigned short* __restrict__ fn) {
  int bs = blockIdx.x;
  int t = threadIdx.x;
  float4 v = ((const float4*)(ssm + (size_t)bs * 1024))[t];
  float s = v.x + v.y + v.z + v.w;
  float ss = v.x * v.x + v.y * v.y + v.z * v.z + v.w * v.w;
  #pragma unroll
  for (int o = 1; o < 64; o <<= 1) { s += __shfl_xor(s, o); ss += __shfl_xor(ss, o); }
  __shared__ float red[8];
  int w = t >> 6;
  if ((t & 63) == 0) { red[w] = s; red[4 + w] = ss; }
  __syncthreads();
  float S = red[0] + red[1] + red[2] + red[3];
  float SS = red[4] + red[5] + red[6] + red[7];
  float m = S * (1.0f / 1024.0f);
  float var = SS * (1.0f / 1024.0f) - m * m;
  float inv = rsqrtf(var + EPSF);
  float4 gv = ((const float4*)g)[t];
  float4 bv = ((const float4*)bta)[t];
  ushort4 o;
  o.x = f2bf((v.x - m) * inv * gv.x + bv.x);
  o.y = f2bf((v.y - m) * inv * gv.y + bv.y);
  o.z = f2bf((v.z - m) * inv * gv.z + bv.z);
  o.w = f2bf((v.w - m) * inv * gv.w + bv.w);
  ((ushort4*)(fn + (size_t)bs * 1024))[t] = o;
}

// ---- pipelined bf16 MFMA GEMM: 128x128 block, triple-buffer LDS,
// depth-2 async prefetch, ONE raw s_barrier/iter, fine vmcnt (AITER-style).
// EPI 0: C(bf16) = gelu(acc+bias[n]); EPI 1: fp32 split-K=2 partials.
template <int EPI>
__global__ __launch_bounds__(256) void k_gemm(
    const unsigned short* __restrict__ A, const unsigned short* __restrict__ Bt,
    const float* __restrict__ bias, void* __restrict__ C, int M, int N, int K) {
  __shared__ __align__(16) unsigned short sA[3][128 * 32];
  __shared__ __align__(16) unsigned short sB[3][128 * 32];
  int m0 = blockIdx.y * 128, n0 = blockIdx.x * 128;
  int ks = (EPI == 1) ? blockIdx.z : 0;
  int kLen = (EPI == 1) ? (K >> 1) : K;
  int kOff = ks * kLen;
  int tid = threadIdx.x;
  int wave = tid >> 6, lane = tid & 63;
  int wr = wave >> 1, wc = wave & 1;
  int l15 = lane & 15, quad = lane >> 4;

  const unsigned short* gA0 = A + (size_t)(m0 + (tid >> 2)) * K + kOff + (tid & 3) * 8;
  const unsigned short* gA1 = gA0 + (size_t)64 * K;
  const unsigned short* gB0 = Bt + (size_t)(n0 + (tid >> 2)) * K + kOff + (tid & 3) * 8;
  const unsigned short* gB1 = gB0 + (size_t)64 * K;
  int lo = (tid & ~63) * 8;  // wave-uniform LDS chunk base (elements)

  f32x4 zero = {0.0f, 0.0f, 0.0f, 0.0f};
  f32x4 acc[4][4];
  #pragma unroll
  for (int i = 0; i < 4; ++i)
    #pragma unroll
    for (int j = 0; j < 4; ++j) acc[i][j] = zero;

  auto issue = [&](int p, int ke) {
    async_load16(gA0 + ke, &sA[p][lo]);
    async_load16(gA1 + ke, &sA[p][64 * 32 + lo]);
    async_load16(gB0 + ke, &sB[p][lo]);
    async_load16(gB1 + ke, &sB[p][64 * 32 + lo]);
  };

  int nIter = kLen >> 5;            // 32 or 64
  issue(0, 0);
  issue(1, 32);
  int bufC = 0, bufI = 2;
  for (int it = 0; it < nIter; ++it) {
    if (it + 1 < nIter) asm volatile("s_waitcnt vmcnt(4)" ::: "memory");
    else                asm volatile("s_waitcnt vmcnt(0)" ::: "memory");
    __builtin_amdgcn_s_barrier();
    if (it + 2 < nIter) issue(bufI, (it + 2) << 5);
    const unsigned short* pa = &sA[bufC][(wr * 64 + l15) * 32 + quad * 8];
    const unsigned short* pb = &sB[bufC][(wc * 64 + l15) * 32 + quad * 8];
    bf16x8 af[4], bfr[4];
    #pragma unroll
    for (int i = 0; i < 4; ++i) af[i] = *(const bf16x8*)(pa + i * 512);
    #pragma unroll
    for (int j = 0; j < 4; ++j) bfr[j] = *(const bf16x8*)(pb + j * 512);
    #pragma unroll
    for (int i = 0; i < 4; ++i)
      #pragma unroll
      for (int j = 0; j < 4; ++j)
        acc[i][j] = __builtin_amdgcn_mfma_f32_16x16x32_bf16(af[i], bfr[j], acc[i][j], 0, 0, 0);
    bufC = (bufC == 2) ? 0 : bufC + 1;
    bufI = (bufI == 2) ? 0 : bufI + 1;
  }

  if (EPI == 0) {
    unsigned short* Cb = (unsigned short*)C;
    #pragma unroll
    for (int i = 0; i < 4; ++i)
      #pragma unroll
      for (int j = 0; j < 4; ++j) {
        int col = n0 + wc * 64 + j * 16 + l15;
        float bval = bias[col];
        #pragma unroll
        for (int v = 0; v < 4; ++v) {
          int row = m0 + wr * 64 + i * 16 + quad * 4 + v;
          float val = acc[i][j][v] + bval;
          val = 0.5f * val * (1.0f + erff(val * 0.70710678118654752f));
          Cb[(size_t)row * N + col] = f2bf(val);
        }
      }
  } else {
    float* dst = (float*)C + (size_t)ks * M * N;
    #pragma unroll
    for (int i = 0; i < 4; ++i)
      #pragma unroll
      for (int j = 0; j < 4; ++j) {
        int col = n0 + wc * 64 + j * 16 + l15;
        #pragma unroll
        for (int v = 0; v < 4; ++v) {
          int row = m0 + wr * 64 + i * 16 + quad * 4 + v;
          dst[(size_t)row * N + col] = acc[i][j][v];
        }
      }
  }
}

// ---- split-K=2 reduce + bias + residual ----
__global__ __launch_bounds__(256) void k_reduce(
    const float* __restrict__ pA, const float* __restrict__ bias,
    const float* __restrict__ res, float* __restrict__ out) {
  int i = blockIdx.x * 256 + threadIdx.x;
  const int MN4 = 524288;
  float4 v = ((const float4*)pA)[i];
  float4 w = ((const float4*)pA)[i + MN4];
  float4 bb = ((const float4*)bias)[i & 255];
  float4 rr = ((const float4*)res)[i];
  float4 o;
  o.x = v.x + w.x + bb.x + rr.x; o.y = v.y + w.y + bb.y + rr.y;
  o.z = v.z + w.z + bb.z + rr.z; o.w = v.w + w.w + bb.w + rr.w;
  ((float4*)out)[i] = o;
}

extern "C" void kernel_launch(void* const* d_in, const int* in_sizes, int n_in,
                              void* d_out, int out_size, void* d_ws, size_t ws_size,
                              hipStream_t stream) {
  const float* x     = (const float*)d_in[0];
  const float* log_A = (const float*)d_in[1];
  const float* w_dt  = (const float*)d_in[2];
  const float* b_dt  = (const float*)d_in[3];
  const float* g_ssm = (const float*)d_in[4];
  const float* b_ssm = (const float*)d_in[5];
  const float* g_ffn = (const float*)d_in[6];
  const float* b_ffn = (const float*)d_in[7];
  const float* W1    = (const float*)d_in[8];
  const float* bb1   = (const float*)d_in[9];
  const float* W2    = (const float*)d_in[10];
  const float* bb2   = (const float*)d_in[11];
  float* out = (float*)d_out;

  const size_t MB = 1u << 20;
  char* ws = (char*)d_ws;
  float* xn            = (float*)(ws);                       // 0-8 (dead after scan1)
  unsigned short* W1t  = (unsigned short*)(ws + 8 * MB);     // 8-16 (dead after gemm1)
  float* loga          = (float*)(ws + 16 * MB);             // 16-16.25
  float4* Ebuf         = (float4*)(ws + 16 * MB + 262144);   // 64 KB
  float* Pbuf          = (float*)(ws + 16 * MB + 393216);    // 2 KB
  unsigned short* fn   = (unsigned short*)(ws + 17 * MB);    // 17-21 (dead after gemm1)
  unsigned short* W2t  = (unsigned short*)(ws + 21 * MB);    // 21-29 (live thru gemm2)
  float* ssm           = (float*)(ws + 29 * MB);             // 29-37 (live to end)
  unsigned short* hbf  = (unsigned short*)(ws + 37 * MB);    // 37-53
  float* pA            = (float*)(ws);                       // 0-16 over xn+W1t (dead)

  k_pre<<<4096, 256, 0, stream>>>(x, g_ssm, b_ssm, w_dt, b_dt, log_A, xn, loga,
                                  W1, W1t, W2, W2t);
  k_scan_pass<0><<<512, 256, 0, stream>>>(xn, x, loga, Ebuf, Pbuf, ssm);
  k_scan_pass<1><<<512, 256, 0, stream>>>(xn, x, loga, Ebuf, Pbuf, ssm);
  k_ln2<<<2048, 256, 0, stream>>>(ssm, g_ffn, b_ffn, fn);
  k_gemm<0><<<dim3(32, 16), 256, 0, stream>>>(fn, W1t, bb1, (void*)hbf, 2048, 4096, 1024);
  k_gemm<1><<<dim3(8, 16, 2), 256, 0, stream>>>(hbf, W2t, nullptr, (void*)pA, 2048, 1024, 4096);
  k_reduce<<<2048, 256, 0, stream>>>(pA, bb2, ssm, out);
}